// Round 1
// baseline (1659.251 us; speedup 1.0000x reference)
//
#include <hip/hip_runtime.h>
#include <hip/hip_bf16.h>
#include <cstddef>

typedef __bf16 bf16x8 __attribute__((ext_vector_type(8)));
typedef __bf16 bf16x4 __attribute__((ext_vector_type(4)));
typedef float v4f __attribute__((ext_vector_type(4)));

#define MFMA16(a, b, c) __builtin_amdgcn_mfma_f32_16x16x32_bf16(a, b, c, 0, 0, 0)

static constexpr int S = 1024, D = 1024, H = 16, DK = 64;
static constexpr int LD = 72;  // LDS row stride (bf16): 144B, 16B-aligned, only 2-way bank alias (free)

__device__ __forceinline__ void cvt4(__bf16* d, v4f v) {
  bf16x4 t = { (__bf16)v[0], (__bf16)v[1], (__bf16)v[2], (__bf16)v[3] };
  *(bf16x4*)d = t;
}

// ---------------- Kernel 1: QKV projections  X @ W^T + b -> bf16 head layout ----------------
// z=0: Q->qh[bh][s][dk], z=1: K->kh[bh][s][dk], z=2: V->vT[bh][dk][s] (transposed for PV B-operand)
__global__ __launch_bounds__(256) void k_proj(
    const float* __restrict__ Q, const float* __restrict__ K, const float* __restrict__ V,
    const float* __restrict__ Wq, const float* __restrict__ bq,
    const float* __restrict__ Wk, const float* __restrict__ bk,
    const float* __restrict__ Wv, const float* __restrict__ bv,
    __bf16* __restrict__ qh, __bf16* __restrict__ kh, __bf16* __restrict__ vT)
{
  __shared__ __bf16 As[128 * LD];
  __shared__ __bf16 Bs[128 * LD];
  const float *X, *W, *bias; __bf16* out; bool tr = false;
  if (blockIdx.z == 0)      { X = Q; W = Wq; bias = bq; out = qh; }
  else if (blockIdx.z == 1) { X = K; W = Wk; bias = bk; out = kh; }
  else                      { X = V; W = Wv; bias = bv; out = vT; tr = true; }
  const int m0 = blockIdx.y * 128, n0 = blockIdx.x * 128;
  const int tid = threadIdx.x, lane = tid & 63, w = tid >> 6;
  const int wm = (w >> 1) * 64, wn = (w & 1) * 64;
  const int lr = lane & 15, qd = lane >> 4;
  v4f acc[4][4] = {};
  for (int k0 = 0; k0 < D; k0 += 64) {
    __syncthreads();
    for (int i = 0; i < 8; i++) {
      int c = tid + i * 256;
      int row = c >> 4, cc = (c & 15) * 4;
      v4f va = *(const v4f*)(X + (size_t)(m0 + row) * D + k0 + cc);
      cvt4(&As[row * LD + cc], va);
      v4f vb = *(const v4f*)(W + (size_t)(n0 + row) * D + k0 + cc);
      cvt4(&Bs[row * LD + cc], vb);
    }
    __syncthreads();
    for (int kk = 0; kk < 2; kk++) {
      bf16x8 af[4], bfr[4];
      for (int t = 0; t < 4; t++) af[t]  = *(const bf16x8*)&As[(wm + t * 16 + lr) * LD + kk * 32 + qd * 8];
      for (int t = 0; t < 4; t++) bfr[t] = *(const bf16x8*)&Bs[(wn + t * 16 + lr) * LD + kk * 32 + qd * 8];
      for (int i = 0; i < 4; i++)
        for (int j = 0; j < 4; j++)
          acc[i][j] = MFMA16(af[i], bfr[j], acc[i][j]);
    }
  }
  for (int j = 0; j < 4; j++) {
    int ng = n0 + wn + j * 16 + lr;
    float bv_ = bias[ng];
    int hh = ng >> 6, dk = ng & 63;
    for (int i = 0; i < 4; i++) {
      int mbase = m0 + wm + i * 16 + qd * 4;
      for (int r = 0; r < 4; r++) {
        int mg = mbase + r;
        int bb = mg >> 10, ss = mg & 1023;
        float val = acc[i][j][r] + bv_;
        size_t idx = tr ? ((size_t)((bb * H + hh) * DK + dk) * S + ss)
                        : ((size_t)(bb * H + hh) * S * DK + (size_t)ss * DK + dk);
        out[idx] = (__bf16)val;
      }
    }
  }
}

// ---------------- Kernel 2: scores = (q @ k^T) * 1/8, mask -> -1e9, write f32 ----------------
__global__ __launch_bounds__(256) void k_scores(
    const __bf16* __restrict__ qh, const __bf16* __restrict__ kh,
    const unsigned char* __restrict__ mask, float* __restrict__ out2)
{
  __shared__ __bf16 Qs[128 * LD];
  __shared__ __bf16 Ks[128 * LD];
  const int bh = blockIdx.z, bb = bh >> 4;
  const int i0 = blockIdx.y * 128, j0 = blockIdx.x * 128;
  const int tid = threadIdx.x, lane = tid & 63, w = tid >> 6;
  const int wm = (w >> 1) * 64, wn = (w & 1) * 64;
  const int lr = lane & 15, qd = lane >> 4;
  const __bf16* qb = qh + (size_t)bh * S * DK;
  const __bf16* kb = kh + (size_t)bh * S * DK;
  for (int i = 0; i < 4; i++) {
    int c = tid + i * 256;
    int row = c >> 3, cc = (c & 7) * 8;
    *(bf16x8*)&Qs[row * LD + cc] = *(const bf16x8*)(qb + (size_t)(i0 + row) * DK + cc);
    *(bf16x8*)&Ks[row * LD + cc] = *(const bf16x8*)(kb + (size_t)(j0 + row) * DK + cc);
  }
  __syncthreads();
  v4f acc[4][4] = {};
  for (int kk = 0; kk < 2; kk++) {
    bf16x8 af[4], bfr[4];
    for (int t = 0; t < 4; t++) af[t]  = *(const bf16x8*)&Qs[(wm + t * 16 + lr) * LD + kk * 32 + qd * 8];
    for (int t = 0; t < 4; t++) bfr[t] = *(const bf16x8*)&Ks[(wn + t * 16 + lr) * LD + kk * 32 + qd * 8];
    for (int i = 0; i < 4; i++)
      for (int j = 0; j < 4; j++)
        acc[i][j] = MFMA16(af[i], bfr[j], acc[i][j]);
  }
  for (int i = 0; i < 4; i++) {
    for (int r = 0; r < 4; r++) {
      int ig = i0 + wm + i * 16 + qd * 4 + r;
      const unsigned char* mrow = mask + (size_t)bb * S * S + (size_t)ig * S;
      float* orow = out2 + ((size_t)bh * S + ig) * S;
      for (int j = 0; j < 4; j++) {
        int jg = j0 + wn + j * 16 + lr;
        float val = acc[i][j][r] * 0.125f;
        if (mrow[jg]) val = -1e9f;
        orow[jg] = val;
      }
    }
  }
}

// ---------------- Kernel 3: row softmax, scores(f32) -> attn(f32) ----------------
__global__ __launch_bounds__(256) void k_softmax(
    const float* __restrict__ scores, float* __restrict__ attn)
{
  const int row = blockIdx.x * 4 + (threadIdx.x >> 6);
  const int lane = threadIdx.x & 63;
  const float* src = scores + (size_t)row * S;
  float* dst = attn + (size_t)row * S;
  v4f v[4];
  float m = -3.4e38f;
  for (int c = 0; c < 4; c++) {
    v[c] = *(const v4f*)(src + c * 256 + lane * 4);
    m = fmaxf(m, fmaxf(fmaxf(v[c][0], v[c][1]), fmaxf(v[c][2], v[c][3])));
  }
  for (int off = 32; off; off >>= 1) m = fmaxf(m, __shfl_xor(m, off));
  float s = 0.f;
  for (int c = 0; c < 4; c++) {
    v[c][0] = __expf(v[c][0] - m);
    v[c][1] = __expf(v[c][1] - m);
    v[c][2] = __expf(v[c][2] - m);
    v[c][3] = __expf(v[c][3] - m);
    s += v[c][0] + v[c][1] + v[c][2] + v[c][3];
  }
  for (int off = 32; off; off >>= 1) s += __shfl_xor(s, off);
  float inv = 1.f / s;
  for (int c = 0; c < 4; c++) {
    v[c] *= inv;
    *(v4f*)(dst + c * 256 + lane * 4) = v[c];
  }
}

// ---------------- Kernel 4: context = attn @ v, per (b,h); vT gives contiguous B-frags ----------------
__global__ __launch_bounds__(256) void k_pv(
    const float* __restrict__ attn, const __bf16* __restrict__ vT, __bf16* __restrict__ ctx)
{
  __shared__ __bf16 As[128 * LD];
  __shared__ __bf16 Bs[64 * LD];
  const int bh = blockIdx.y, i0 = blockIdx.x * 128;
  const int bb = bh >> 4, hh = bh & 15;
  const int tid = threadIdx.x, lane = tid & 63, w = tid >> 6;
  const int wm = w * 32;
  const int lr = lane & 15, qd = lane >> 4;
  const float* Ab = attn + ((size_t)bh * S + i0) * S;
  const __bf16* Bb = vT + (size_t)bh * DK * S;
  v4f acc[2][4] = {};
  for (int j0 = 0; j0 < S; j0 += 64) {
    __syncthreads();
    for (int i = 0; i < 8; i++) {
      int c = tid + i * 256;
      int row = c >> 4, cc = (c & 15) * 4;
      v4f va = *(const v4f*)(Ab + (size_t)row * S + j0 + cc);
      cvt4(&As[row * LD + cc], va);
    }
    for (int i = 0; i < 2; i++) {
      int c = tid + i * 256;
      int row = c >> 3, cc = (c & 7) * 8;
      *(bf16x8*)&Bs[row * LD + cc] = *(const bf16x8*)(Bb + (size_t)row * S + j0 + cc);
    }
    __syncthreads();
    for (int kk = 0; kk < 2; kk++) {
      bf16x8 af[2], bfr[4];
      for (int t = 0; t < 2; t++) af[t]  = *(const bf16x8*)&As[(wm + t * 16 + lr) * LD + kk * 32 + qd * 8];
      for (int t = 0; t < 4; t++) bfr[t] = *(const bf16x8*)&Bs[(t * 16 + lr) * LD + kk * 32 + qd * 8];
      for (int i = 0; i < 2; i++)
        for (int j = 0; j < 4; j++)
          acc[i][j] = MFMA16(af[i], bfr[j], acc[i][j]);
    }
  }
  for (int i = 0; i < 2; i++) {
    for (int r = 0; r < 4; r++) {
      int ss = i0 + wm + i * 16 + qd * 4 + r;
      __bf16* crow = ctx + ((size_t)bb * S + ss) * D + hh * DK;
      for (int j = 0; j < 4; j++) {
        int dk = j * 16 + lr;
        crow[dk] = (__bf16)acc[i][j][r];
      }
    }
  }
}

// ---------------- Kernel 5: out0 = ctx @ Wo^T + bo + Q ----------------
__global__ __launch_bounds__(256) void k_outproj(
    const __bf16* __restrict__ ctx, const float* __restrict__ Wo, const float* __restrict__ bo,
    const float* __restrict__ Qin, float* __restrict__ out0)
{
  __shared__ __bf16 As[128 * LD];
  __shared__ __bf16 Bs[128 * LD];
  const int m0 = blockIdx.y * 128, n0 = blockIdx.x * 128;
  const int tid = threadIdx.x, lane = tid & 63, w = tid >> 6;
  const int wm = (w >> 1) * 64, wn = (w & 1) * 64;
  const int lr = lane & 15, qd = lane >> 4;
  v4f acc[4][4] = {};
  for (int k0 = 0; k0 < D; k0 += 64) {
    __syncthreads();
    for (int i = 0; i < 4; i++) {
      int c = tid + i * 256;
      int row = c >> 3, cc = (c & 7) * 8;
      *(bf16x8*)&As[row * LD + cc] = *(const bf16x8*)(ctx + (size_t)(m0 + row) * D + k0 + cc);
    }
    for (int i = 0; i < 8; i++) {
      int c = tid + i * 256;
      int row = c >> 4, cc = (c & 15) * 4;
      v4f vb = *(const v4f*)(Wo + (size_t)(n0 + row) * D + k0 + cc);
      cvt4(&Bs[row * LD + cc], vb);
    }
    __syncthreads();
    for (int kk = 0; kk < 2; kk++) {
      bf16x8 af[4], bfr[4];
      for (int t = 0; t < 4; t++) af[t]  = *(const bf16x8*)&As[(wm + t * 16 + lr) * LD + kk * 32 + qd * 8];
      for (int t = 0; t < 4; t++) bfr[t] = *(const bf16x8*)&Bs[(wn + t * 16 + lr) * LD + kk * 32 + qd * 8];
      for (int i = 0; i < 4; i++)
        for (int j = 0; j < 4; j++)
          acc[i][j] = MFMA16(af[i], bfr[j], acc[i][j]);
    }
  }
  for (int j = 0; j < 4; j++) {
    int ng = n0 + wn + j * 16 + lr;
    float bv_ = bo[ng];
    for (int i = 0; i < 4; i++) {
      for (int r = 0; r < 4; r++) {
        int mg = m0 + wm + i * 16 + qd * 4 + r;
        size_t idx = (size_t)mg * D + ng;
        out0[idx] = acc[i][j][r] + bv_ + Qin[idx];
      }
    }
  }
}

extern "C" void kernel_launch(void* const* d_in, const int* in_sizes, int n_in,
                              void* d_out, int out_size, void* d_ws, size_t ws_size,
                              hipStream_t stream)
{
  const float* Q  = (const float*)d_in[0];
  const float* K  = (const float*)d_in[1];
  const float* V  = (const float*)d_in[2];
  const unsigned char* mask = (const unsigned char*)d_in[3];
  const float* Wq = (const float*)d_in[4];
  const float* bq = (const float*)d_in[5];
  const float* Wk = (const float*)d_in[6];
  const float* bk = (const float*)d_in[7];
  const float* Wv = (const float*)d_in[8];
  const float* bv = (const float*)d_in[9];
  const float* Wo = (const float*)d_in[10];
  const float* bo = (const float*)d_in[11];

  float* out0 = (float*)d_out;                        // output + Q : [8,1024,1024]
  float* out1 = out0 + (size_t)8 * 1024 * 1024;       // attn       : [8,16,1024,1024]
  float* out2 = out1 + (size_t)8 * 16 * 1024 * 1024;  // scores     : [8,16,1024,1024]

  __bf16* qh  = (__bf16*)d_ws;                        // [bh][s][dk]
  __bf16* kh  = qh + (size_t)8 * 1024 * 1024;         // [bh][s][dk]
  __bf16* vT  = kh + (size_t)8 * 1024 * 1024;         // [bh][dk][s]
  __bf16* ctx = vT + (size_t)8 * 1024 * 1024;         // [b*s][h*dk]

  k_proj<<<dim3(8, 64, 3), 256, 0, stream>>>(Q, K, V, Wq, bq, Wk, bk, Wv, bv, qh, kh, vT);
  k_scores<<<dim3(8, 8, 128), 256, 0, stream>>>(qh, kh, mask, out2);
  k_softmax<<<dim3(32768), 256, 0, stream>>>(out2, out1);
  k_pv<<<dim3(8, 128), 256, 0, stream>>>(out1, vT, ctx);
  k_outproj<<<dim3(8, 64), 256, 0, stream>>>(ctx, Wo, bo, Q, out0);
}